// Round 3
// baseline (534.321 us; speedup 1.0000x reference)
//
#include <hip/hip_runtime.h>

typedef __attribute__((ext_vector_type(8))) short short8;
typedef __attribute__((ext_vector_type(4))) short short4v;
typedef __attribute__((ext_vector_type(4))) float float4v;
typedef __attribute__((ext_vector_type(4))) unsigned int uint4v;

#define DEV static __device__ __forceinline__

DEV float b2f(unsigned short u) { return __uint_as_float(((unsigned)u) << 16); }
DEV unsigned short f2b(float f) {
  return __builtin_bit_cast(unsigned short, static_cast<__bf16>(f));
}
DEV unsigned pk2(float lo, float hi) {
  return (unsigned)f2b(lo) | ((unsigned)f2b(hi) << 16);
}

// ws layout (2-byte units):
// [0, 49152)      qkv_w bf16  [384][128]   (out_col, k) k-contiguous
// [49152, 65536)  proj_w bf16 [128][128]
// [65536, 81920)  biasM bf16  [4][64 q-row][64 key]  row-major
__global__ void prep_kernel(const float* __restrict__ qkvw, const float* __restrict__ projw,
                            const float* __restrict__ btab, const int* __restrict__ ridx,
                            unsigned short* __restrict__ ws) {
  int t = blockIdx.x * blockDim.x + threadIdx.x;
  int nt = gridDim.x * blockDim.x;
  for (int i = t; i < 49152; i += nt) ws[i] = f2b(qkvw[i]);
  for (int i = t; i < 16384; i += nt) ws[49152 + i] = f2b(projw[i]);
  for (int i = t; i < 16384; i += nt) {
    int h = i >> 12, r = i & 4095;
    ws[65536 + i] = f2b(btab[ridx[r] * 4 + h]);
  }
}

#define LOG2E 1.44269504088896340736f
#define QSCALE 0.17677669529663687f  // 32^-0.5

// In-register acc->frag transform.
// Input: lane (g=lane>>4, l15) holds T[4g+j][l15] (A0) and T[16+4g+j][l15] (A1), j=0..3.
// Output: lane holds bf16 T[8*(lane>>4)+m][l15], m=0..7 (the MFMA A/B-frag layout).
DEV short8 xform(float4v A0, float4v A1, int lane) {
  unsigned p0 = pk2(A0[0], A0[1]), p1 = pk2(A0[2], A0[3]);
  unsigned p2 = pk2(A1[0], A1[1]), p3 = pk2(A1[2], A1[3]);
  int srcA = (((lane >> 4) & 1) << 5) | (lane & 15);
  int srcB = srcA + 16;
  unsigned a0 = (unsigned)__shfl((int)p0, srcA);
  unsigned c0 = (unsigned)__shfl((int)p2, srcA);
  unsigned a1 = (unsigned)__shfl((int)p1, srcA);
  unsigned c1 = (unsigned)__shfl((int)p3, srcA);
  unsigned a2 = (unsigned)__shfl((int)p0, srcB);
  unsigned c2 = (unsigned)__shfl((int)p2, srcB);
  unsigned a3 = (unsigned)__shfl((int)p1, srcB);
  unsigned c3 = (unsigned)__shfl((int)p3, srcB);
  bool hi = lane >= 32;
  uint4v w;
  w[0] = hi ? c0 : a0; w[1] = hi ? c1 : a1;
  w[2] = hi ? c2 : a2; w[3] = hi ? c3 : a3;
  return __builtin_bit_cast(short8, w);
}

__global__ __launch_bounds__(256, 4)
void win_attn_kernel(const float* __restrict__ x, const float* __restrict__ mask,
                     const float* __restrict__ qkv_b, const float* __restrict__ proj_b,
                     const unsigned short* __restrict__ ws, float* __restrict__ out) {
  // LDS: single 16KB tile [64][128] bf16, swizzled: holds x, later attn_out.
  __shared__ short sm[8192];

  const int b = blockIdx.x;
  const int tid = threadIdx.x;
  const int h = tid >> 6;       // wave id == head
  const int lane = tid & 63;
  const int l15 = lane & 15;
  const int g = lane >> 4;
  const int g1 = g & 1, g2 = g >> 1;
  const int wm = b & 1023;

  // ---------------- phase 0: stage x (bf16, swizzled) ------------------------
  {
    const float4* xw = (const float4*)(x + (size_t)b * 8192);
#pragma unroll
    for (int it = 0; it < 4; ++it) {
      int c = it * 256 + tid;           // 8-elem chunk 0..1023
      int row = c >> 4, ch = c & 15;
      float4 a0 = xw[c * 2], a1 = xw[c * 2 + 1];
      short8 v;
      v[0] = (short)f2b(a0.x); v[1] = (short)f2b(a0.y);
      v[2] = (short)f2b(a0.z); v[3] = (short)f2b(a0.w);
      v[4] = (short)f2b(a1.x); v[5] = (short)f2b(a1.y);
      v[6] = (short)f2b(a1.z); v[7] = (short)f2b(a1.w);
      *(short8*)&sm[row * 128 + ((ch ^ (row & 7)) << 3)] = v;
    }
  }
  __syncthreads();

  // x A-frag read: lane holds x[16ri+l15][32kt+8g .. +7]
#define LDA(kt, ri) (*(const short8*)&sm[(16 * (ri) + l15) * 128 + ((((kt)*4 + g) ^ (l15 & 7)) << 3)])

  // ---------------- pass 1: q,k = W_{q,k} x^T (swapped) ----------------------
  float4v aq[2][2][4];  // [q/k][oc][ri]: lane holds out[d=16oc+4g+j][token=16ri+l15]
#pragma unroll
  for (int mt = 0; mt < 2; ++mt)
#pragma unroll
    for (int oc = 0; oc < 2; ++oc)
#pragma unroll
      for (int ri = 0; ri < 4; ++ri) {
        aq[mt][oc][ri][0]=0.f; aq[mt][oc][ri][1]=0.f; aq[mt][oc][ri][2]=0.f; aq[mt][oc][ri][3]=0.f;
      }
#pragma unroll
  for (int kt = 0; kt < 4; ++kt) {
    short8 af[4];
#pragma unroll
    for (int ri = 0; ri < 4; ++ri) af[ri] = LDA(kt, ri);
#pragma unroll
    for (int mt = 0; mt < 2; ++mt)
#pragma unroll
      for (int oc = 0; oc < 2; ++oc) {
        short8 w = *(const short8*)&ws[(mt * 128 + h * 32 + oc * 16 + l15) * 128 + kt * 32 + g * 8];
#pragma unroll
        for (int ri = 0; ri < 4; ++ri)
          aq[mt][oc][ri] = __builtin_amdgcn_mfma_f32_16x16x32_bf16(w, af[ri], aq[mt][oc][ri], 0, 0, 0);
      }
  }
  // bias (+scale for q), then in-register conversion to S operand frags
  short8 qa[4], ka[4];
  {
    float4v bq[2], bk[2];
#pragma unroll
    for (int oc = 0; oc < 2; ++oc) {
      bq[oc] = *(const float4v*)&qkv_b[h * 32 + oc * 16 + 4 * g];
      bk[oc] = *(const float4v*)&qkv_b[128 + h * 32 + oc * 16 + 4 * g];
    }
#pragma unroll
    for (int ri = 0; ri < 4; ++ri) {
#pragma unroll
      for (int oc = 0; oc < 2; ++oc)
#pragma unroll
        for (int j = 0; j < 4; ++j) {
          aq[0][oc][ri][j] = (aq[0][oc][ri][j] + bq[oc][j]) * QSCALE;
          aq[1][oc][ri][j] += bk[oc][j];
        }
      qa[ri] = xform(aq[0][0][ri], aq[0][1][ri], lane);
      ka[ri] = xform(aq[1][0][ri], aq[1][1][ri], lane);
    }
  }

  // ---------------- pass 2: v = x W_v^T (unswapped) --------------------------
  float4v av[2][4];  // [oc][ri]: lane holds v[token=16ri+4g+j][d=16oc+l15]
#pragma unroll
  for (int oc = 0; oc < 2; ++oc)
#pragma unroll
    for (int ri = 0; ri < 4; ++ri) { av[oc][ri][0]=0.f; av[oc][ri][1]=0.f; av[oc][ri][2]=0.f; av[oc][ri][3]=0.f; }
#pragma unroll
  for (int kt = 0; kt < 4; ++kt) {
    short8 af[4];
#pragma unroll
    for (int ri = 0; ri < 4; ++ri) af[ri] = LDA(kt, ri);
#pragma unroll
    for (int oc = 0; oc < 2; ++oc) {
      short8 w = *(const short8*)&ws[(256 + h * 32 + oc * 16 + l15) * 128 + kt * 32 + g * 8];
#pragma unroll
      for (int ri = 0; ri < 4; ++ri)
        av[oc][ri] = __builtin_amdgcn_mfma_f32_16x16x32_bf16(af[ri], w, av[oc][ri], 0, 0, 0);
    }
  }
  short8 va[2][2];  // [dt][hf]: V^T frag, lane holds V[key=32hf+8g+m][d=16dt+l15]
  {
    float bv0 = qkv_b[256 + h * 32 + l15];
    float bv1 = qkv_b[256 + h * 32 + 16 + l15];
#pragma unroll
    for (int ri = 0; ri < 4; ++ri)
#pragma unroll
      for (int j = 0; j < 4; ++j) { av[0][ri][j] += bv0; av[1][ri][j] += bv1; }
#pragma unroll
    for (int dt = 0; dt < 2; ++dt)
#pragma unroll
      for (int hf = 0; hf < 2; ++hf)
        va[dt][hf] = xform(av[dt][2 * hf], av[dt][2 * hf + 1], lane);
  }

  // ---------------- S + softmax + PV, fused per token-block ri ---------------
  const unsigned short* bt = ws + 65536 + h * 4096;
  const float* mrow = mask + (size_t)wm * 4096;
  float4v ot[2][4];  // [dt][ri]: lane holds o[d=16dt+4g+j][token=16ri+l15] (unnormalized)
#pragma unroll
  for (int dt = 0; dt < 2; ++dt)
#pragma unroll
    for (int ri = 0; ri < 4; ++ri) { ot[dt][ri][0]=0.f; ot[dt][ri][1]=0.f; ot[dt][ri][2]=0.f; ot[dt][ri][3]=0.f; }
  float rs[4];
#pragma unroll
  for (int ri = 0; ri < 4; ++ri) {
    int row = 16 * ri + l15;
    float4v st[4];
#pragma unroll
    for (int ci = 0; ci < 4; ++ci) {
      float4 mk = *(const float4*)&mrow[row * 64 + ci * 16 + 4 * g];
      const unsigned short* bp = bt + row * 64 + ci * 16 + 4 * g;
      float4v c;
      c[0] = mk.x + b2f(bp[0]); c[1] = mk.y + b2f(bp[1]);
      c[2] = mk.z + b2f(bp[2]); c[3] = mk.w + b2f(bp[3]);
      st[ci] = __builtin_amdgcn_mfma_f32_16x16x32_bf16(ka[ci], qa[ri], c, 0, 0, 0);
    }
    // softmax over keys for token row: 16 per-lane values + reduce over g
    float m = st[0][0];
#pragma unroll
    for (int ci = 0; ci < 4; ++ci)
#pragma unroll
      for (int j = 0; j < 4; ++j) m = fmaxf(m, st[ci][j]);
    m = fmaxf(m, __shfl_xor(m, 16));
    m = fmaxf(m, __shfl_xor(m, 32));
    float mL = m * LOG2E;
    float sum = 0.f;
#pragma unroll
    for (int ci = 0; ci < 4; ++ci)
#pragma unroll
      for (int j = 0; j < 4; ++j) {
        float p = exp2f(__builtin_fmaf(st[ci][j], LOG2E, -mL));
        st[ci][j] = p;
        sum += p;
      }
    sum += __shfl_xor(sum, 16);
    sum += __shfl_xor(sum, 32);
    rs[ri] = __builtin_amdgcn_rcpf(sum);
    // P frags (unnormalized, values <=1) + PV accumulate
#pragma unroll
    for (int hf = 0; hf < 2; ++hf) {
      short8 pb = xform(st[2 * hf], st[2 * hf + 1], lane);
      ot[0][ri] = __builtin_amdgcn_mfma_f32_16x16x32_bf16(va[0][hf], pb, ot[0][ri], 0, 0, 0);
      ot[1][ri] = __builtin_amdgcn_mfma_f32_16x16x32_bf16(va[1][hf], pb, ot[1][ri], 0, 0, 0);
    }
  }

  __syncthreads();  // all waves done reading x from LDS
  // attn_out (normalized by rs): lane owns token row 16ri+l15, cols 32h+16dt+4g+{0..3}
#pragma unroll
  for (int dt = 0; dt < 2; ++dt) {
    int ch = 4 * h + 2 * dt + g2;
#pragma unroll
    for (int ri = 0; ri < 4; ++ri) {
      int row = 16 * ri + l15;
      short4v pv;
#pragma unroll
      for (int j = 0; j < 4; ++j) pv[j] = (short)f2b(ot[dt][ri][j] * rs[ri]);
      *(short4v*)&sm[row * 128 + ((ch ^ (row & 7)) << 3) + 4 * g1] = pv;
    }
  }
  __syncthreads();

  // ---------------- output projection (swapped) ------------------------------
  float4v po[2][4];
#pragma unroll
  for (int oc = 0; oc < 2; ++oc)
#pragma unroll
    for (int ri = 0; ri < 4; ++ri) { po[oc][ri][0]=0.f; po[oc][ri][1]=0.f; po[oc][ri][2]=0.f; po[oc][ri][3]=0.f; }
#pragma unroll
  for (int kt = 0; kt < 4; ++kt) {
    short8 af[4];
#pragma unroll
    for (int ri = 0; ri < 4; ++ri) af[ri] = LDA(kt, ri);
#pragma unroll
    for (int oc = 0; oc < 2; ++oc) {
      short8 w = *(const short8*)&ws[49152 + (h * 32 + oc * 16 + l15) * 128 + kt * 32 + g * 8];
#pragma unroll
      for (int ri = 0; ri < 4; ++ri)
        po[oc][ri] = __builtin_amdgcn_mfma_f32_16x16x32_bf16(w, af[ri], po[oc][ri], 0, 0, 0);
    }
  }
  float* ob = out + (size_t)b * 8192;
#pragma unroll
  for (int oc = 0; oc < 2; ++oc) {
    float4v pb4 = *(const float4v*)&proj_b[h * 32 + oc * 16 + 4 * g];
#pragma unroll
    for (int ri = 0; ri < 4; ++ri) {
      int row = 16 * ri + l15;
      float4 o = make_float4(po[oc][ri][0] + pb4[0], po[oc][ri][1] + pb4[1],
                             po[oc][ri][2] + pb4[2], po[oc][ri][3] + pb4[3]);
      *(float4*)&ob[row * 128 + h * 32 + oc * 16 + 4 * g] = o;
    }
  }
#undef LDA
}

extern "C" void kernel_launch(void* const* d_in, const int* in_sizes, int n_in,
                              void* d_out, int out_size, void* d_ws, size_t ws_size,
                              hipStream_t stream) {
  const float* x      = (const float*)d_in[0];
  const float* mask   = (const float*)d_in[1];
  const float* qkv_w  = (const float*)d_in[2];
  const float* qkv_b  = (const float*)d_in[3];
  const float* proj_w = (const float*)d_in[4];
  const float* proj_b = (const float*)d_in[5];
  const float* btab   = (const float*)d_in[6];
  const int*   ridx   = (const int*)d_in[7];
  unsigned short* ws  = (unsigned short*)d_ws;
  float* out = (float*)d_out;

  hipLaunchKernelGGL(prep_kernel, dim3(64), dim3(256), 0, stream, qkv_w, proj_w, btab, ridx, ws);
  hipLaunchKernelGGL(win_attn_kernel, dim3(8192), dim3(256), 0, stream,
                     x, mask, qkv_b, proj_b, ws, out);
}

// Round 4
// 310.217 us; speedup vs baseline: 1.7224x; 1.7224x over previous
//
#include <hip/hip_runtime.h>

typedef __attribute__((ext_vector_type(8))) short short8;
typedef __attribute__((ext_vector_type(4))) short short4v;
typedef __attribute__((ext_vector_type(4))) float float4v;
typedef __attribute__((ext_vector_type(4))) unsigned int uint4v;

#define DEV static __device__ __forceinline__

DEV float b2f(unsigned short u) { return __uint_as_float(((unsigned)u) << 16); }
DEV unsigned short f2b(float f) {
  return __builtin_bit_cast(unsigned short, static_cast<__bf16>(f));
}
DEV unsigned pk2(float lo, float hi) {
  return (unsigned)f2b(lo) | ((unsigned)f2b(hi) << 16);
}

// ws layout (2-byte units):
// [0, 49152)      qkv_w bf16  [384][128]   (out_col, k) k-contiguous
// [49152, 65536)  proj_w bf16 [128][128]
// [65536, 81920)  biasM bf16  [4][64 q-row][64 key]  row-major
__global__ void prep_kernel(const float* __restrict__ qkvw, const float* __restrict__ projw,
                            const float* __restrict__ btab, const int* __restrict__ ridx,
                            unsigned short* __restrict__ ws) {
  int t = blockIdx.x * blockDim.x + threadIdx.x;
  int nt = gridDim.x * blockDim.x;
  for (int i = t; i < 49152; i += nt) ws[i] = f2b(qkvw[i]);
  for (int i = t; i < 16384; i += nt) ws[49152 + i] = f2b(projw[i]);
  for (int i = t; i < 16384; i += nt) {
    int h = i >> 12, r = i & 4095;
    ws[65536 + i] = f2b(btab[ridx[r] * 4 + h]);
  }
}

#define LOG2E 1.44269504088896340736f
#define QSCALE 0.17677669529663687f  // 32^-0.5

// In-register acc->frag transform.
// Input: lane (g=lane>>4, l15) holds T[4g+j][l15] (A0) and T[16+4g+j][l15] (A1), j=0..3.
// Output: lane holds bf16 T[8*(lane>>4)+m][l15], m=0..7 (the MFMA A/B-frag layout).
DEV short8 xform(float4v A0, float4v A1, int lane) {
  unsigned p0 = pk2(A0[0], A0[1]), p1 = pk2(A0[2], A0[3]);
  unsigned p2 = pk2(A1[0], A1[1]), p3 = pk2(A1[2], A1[3]);
  int srcA = (((lane >> 4) & 1) << 5) | (lane & 15);
  int srcB = srcA + 16;
  unsigned a0 = (unsigned)__shfl((int)p0, srcA);
  unsigned c0 = (unsigned)__shfl((int)p2, srcA);
  unsigned a1 = (unsigned)__shfl((int)p1, srcA);
  unsigned c1 = (unsigned)__shfl((int)p3, srcA);
  unsigned a2 = (unsigned)__shfl((int)p0, srcB);
  unsigned c2 = (unsigned)__shfl((int)p2, srcB);
  unsigned a3 = (unsigned)__shfl((int)p1, srcB);
  unsigned c3 = (unsigned)__shfl((int)p3, srcB);
  bool hi = lane >= 32;
  uint4v w;
  w[0] = hi ? c0 : a0; w[1] = hi ? c1 : a1;
  w[2] = hi ? c2 : a2; w[3] = hi ? c3 : a3;
  return __builtin_bit_cast(short8, w);
}

__global__ __launch_bounds__(256, 3)
void win_attn_kernel(const float* __restrict__ x, const float* __restrict__ mask,
                     const float* __restrict__ qkv_b, const float* __restrict__ proj_b,
                     const unsigned short* __restrict__ ws, float* __restrict__ out) {
  // LDS: single 16KB tile [64][128] bf16, swizzled: holds x, later attn_out.
  __shared__ short sm[8192];

  const int b = blockIdx.x;
  const int tid = threadIdx.x;
  const int h = tid >> 6;       // wave id == head
  const int lane = tid & 63;
  const int l15 = lane & 15;
  const int g = lane >> 4;
  const int g1 = g & 1, g2 = g >> 1;
  const int wm = b & 1023;

  // ---------------- phase 0: stage x (bf16, swizzled) ------------------------
  {
    const float4* xw = (const float4*)(x + (size_t)b * 8192);
#pragma unroll
    for (int it = 0; it < 4; ++it) {
      int c = it * 256 + tid;           // 8-elem chunk 0..1023
      int row = c >> 4, ch = c & 15;
      float4 a0 = xw[c * 2], a1 = xw[c * 2 + 1];
      short8 v;
      v[0] = (short)f2b(a0.x); v[1] = (short)f2b(a0.y);
      v[2] = (short)f2b(a0.z); v[3] = (short)f2b(a0.w);
      v[4] = (short)f2b(a1.x); v[5] = (short)f2b(a1.y);
      v[6] = (short)f2b(a1.z); v[7] = (short)f2b(a1.w);
      *(short8*)&sm[row * 128 + ((ch ^ (row & 7)) << 3)] = v;
    }
  }
  __syncthreads();

  // x A-frag read: lane holds x[16ri+l15][32kt+8g .. +7]
#define LDA(kt, ri) (*(const short8*)&sm[(16 * (ri) + l15) * 128 + ((((kt)*4 + g) ^ (l15 & 7)) << 3)])

  // ---------------- pass 1: q,k = W_{q,k} x^T (swapped) ----------------------
  float4v aq[2][2][4];  // [q/k][oc][ri]: lane holds out[d=16oc+4g+j][token=16ri+l15]
#pragma unroll
  for (int mt = 0; mt < 2; ++mt)
#pragma unroll
    for (int oc = 0; oc < 2; ++oc)
#pragma unroll
      for (int ri = 0; ri < 4; ++ri) {
        aq[mt][oc][ri][0]=0.f; aq[mt][oc][ri][1]=0.f; aq[mt][oc][ri][2]=0.f; aq[mt][oc][ri][3]=0.f;
      }
#pragma unroll
  for (int kt = 0; kt < 4; ++kt) {
    short8 af[4];
#pragma unroll
    for (int ri = 0; ri < 4; ++ri) af[ri] = LDA(kt, ri);
#pragma unroll
    for (int mt = 0; mt < 2; ++mt)
#pragma unroll
      for (int oc = 0; oc < 2; ++oc) {
        short8 w = *(const short8*)&ws[(mt * 128 + h * 32 + oc * 16 + l15) * 128 + kt * 32 + g * 8];
#pragma unroll
        for (int ri = 0; ri < 4; ++ri)
          aq[mt][oc][ri] = __builtin_amdgcn_mfma_f32_16x16x32_bf16(w, af[ri], aq[mt][oc][ri], 0, 0, 0);
      }
  }
  // bias (+scale for q), then in-register conversion to S operand frags
  short8 qa[4], ka[4];
  {
    float4v bq[2], bk[2];
#pragma unroll
    for (int oc = 0; oc < 2; ++oc) {
      bq[oc] = *(const float4v*)&qkv_b[h * 32 + oc * 16 + 4 * g];
      bk[oc] = *(const float4v*)&qkv_b[128 + h * 32 + oc * 16 + 4 * g];
    }
#pragma unroll
    for (int ri = 0; ri < 4; ++ri) {
#pragma unroll
      for (int oc = 0; oc < 2; ++oc)
#pragma unroll
        for (int j = 0; j < 4; ++j) {
          aq[0][oc][ri][j] = (aq[0][oc][ri][j] + bq[oc][j]) * QSCALE;
          aq[1][oc][ri][j] += bk[oc][j];
        }
      qa[ri] = xform(aq[0][0][ri], aq[0][1][ri], lane);
      ka[ri] = xform(aq[1][0][ri], aq[1][1][ri], lane);
    }
  }

  // ---------------- pass 2: v = x W_v^T (unswapped) --------------------------
  float4v av[2][4];  // [oc][ri]: lane holds v[token=16ri+4g+j][d=16oc+l15]
#pragma unroll
  for (int oc = 0; oc < 2; ++oc)
#pragma unroll
    for (int ri = 0; ri < 4; ++ri) { av[oc][ri][0]=0.f; av[oc][ri][1]=0.f; av[oc][ri][2]=0.f; av[oc][ri][3]=0.f; }
#pragma unroll
  for (int kt = 0; kt < 4; ++kt) {
    short8 af[4];
#pragma unroll
    for (int ri = 0; ri < 4; ++ri) af[ri] = LDA(kt, ri);
#pragma unroll
    for (int oc = 0; oc < 2; ++oc) {
      short8 w = *(const short8*)&ws[(256 + h * 32 + oc * 16 + l15) * 128 + kt * 32 + g * 8];
#pragma unroll
      for (int ri = 0; ri < 4; ++ri)
        av[oc][ri] = __builtin_amdgcn_mfma_f32_16x16x32_bf16(af[ri], w, av[oc][ri], 0, 0, 0);
    }
  }
  short8 va[2][2];  // [dt][hf]: V^T frag, lane holds V[key=32hf+8g+m][d=16dt+l15]
  {
    float bv0 = qkv_b[256 + h * 32 + l15];
    float bv1 = qkv_b[256 + h * 32 + 16 + l15];
#pragma unroll
    for (int ri = 0; ri < 4; ++ri)
#pragma unroll
      for (int j = 0; j < 4; ++j) { av[0][ri][j] += bv0; av[1][ri][j] += bv1; }
#pragma unroll
    for (int dt = 0; dt < 2; ++dt)
#pragma unroll
      for (int hf = 0; hf < 2; ++hf)
        va[dt][hf] = xform(av[dt][2 * hf], av[dt][2 * hf + 1], lane);
  }

  // ---------------- S + softmax + PV, fused per token-block ri ---------------
  const unsigned short* bt = ws + 65536 + h * 4096;
  const float* mrow = mask + (size_t)wm * 4096;
  float4v ot[2][4];  // [dt][ri]: lane holds o[d=16dt+4g+j][token=16ri+l15] (unnormalized)
#pragma unroll
  for (int dt = 0; dt < 2; ++dt)
#pragma unroll
    for (int ri = 0; ri < 4; ++ri) { ot[dt][ri][0]=0.f; ot[dt][ri][1]=0.f; ot[dt][ri][2]=0.f; ot[dt][ri][3]=0.f; }
  float rs[4];
#pragma unroll
  for (int ri = 0; ri < 4; ++ri) {
    int row = 16 * ri + l15;
    float4v st[4];
#pragma unroll
    for (int ci = 0; ci < 4; ++ci) {
      float4 mk = *(const float4*)&mrow[row * 64 + ci * 16 + 4 * g];
      const unsigned short* bp = bt + row * 64 + ci * 16 + 4 * g;
      float4v c;
      c[0] = mk.x + b2f(bp[0]); c[1] = mk.y + b2f(bp[1]);
      c[2] = mk.z + b2f(bp[2]); c[3] = mk.w + b2f(bp[3]);
      st[ci] = __builtin_amdgcn_mfma_f32_16x16x32_bf16(ka[ci], qa[ri], c, 0, 0, 0);
    }
    // softmax over keys for token row: 16 per-lane values + reduce over g
    float m = st[0][0];
#pragma unroll
    for (int ci = 0; ci < 4; ++ci)
#pragma unroll
      for (int j = 0; j < 4; ++j) m = fmaxf(m, st[ci][j]);
    m = fmaxf(m, __shfl_xor(m, 16));
    m = fmaxf(m, __shfl_xor(m, 32));
    float mL = m * LOG2E;
    float sum = 0.f;
#pragma unroll
    for (int ci = 0; ci < 4; ++ci)
#pragma unroll
      for (int j = 0; j < 4; ++j) {
        float p = exp2f(__builtin_fmaf(st[ci][j], LOG2E, -mL));
        st[ci][j] = p;
        sum += p;
      }
    sum += __shfl_xor(sum, 16);
    sum += __shfl_xor(sum, 32);
    rs[ri] = __builtin_amdgcn_rcpf(sum);
    // P frags (unnormalized, values <=1) + PV accumulate
#pragma unroll
    for (int hf = 0; hf < 2; ++hf) {
      short8 pb = xform(st[2 * hf], st[2 * hf + 1], lane);
      ot[0][ri] = __builtin_amdgcn_mfma_f32_16x16x32_bf16(va[0][hf], pb, ot[0][ri], 0, 0, 0);
      ot[1][ri] = __builtin_amdgcn_mfma_f32_16x16x32_bf16(va[1][hf], pb, ot[1][ri], 0, 0, 0);
    }
  }

  __syncthreads();  // all waves done reading x from LDS
  // attn_out (normalized by rs): lane owns token row 16ri+l15, cols 32h+16dt+4g+{0..3}
#pragma unroll
  for (int dt = 0; dt < 2; ++dt) {
    int ch = 4 * h + 2 * dt + g2;
#pragma unroll
    for (int ri = 0; ri < 4; ++ri) {
      int row = 16 * ri + l15;
      short4v pv;
#pragma unroll
      for (int j = 0; j < 4; ++j) pv[j] = (short)f2b(ot[dt][ri][j] * rs[ri]);
      *(short4v*)&sm[row * 128 + ((ch ^ (row & 7)) << 3) + 4 * g1] = pv;
    }
  }
  __syncthreads();

  // ---------------- output projection (swapped) ------------------------------
  float4v po[2][4];
#pragma unroll
  for (int oc = 0; oc < 2; ++oc)
#pragma unroll
    for (int ri = 0; ri < 4; ++ri) { po[oc][ri][0]=0.f; po[oc][ri][1]=0.f; po[oc][ri][2]=0.f; po[oc][ri][3]=0.f; }
#pragma unroll
  for (int kt = 0; kt < 4; ++kt) {
    short8 af[4];
#pragma unroll
    for (int ri = 0; ri < 4; ++ri) af[ri] = LDA(kt, ri);
#pragma unroll
    for (int oc = 0; oc < 2; ++oc) {
      short8 w = *(const short8*)&ws[49152 + (h * 32 + oc * 16 + l15) * 128 + kt * 32 + g * 8];
#pragma unroll
      for (int ri = 0; ri < 4; ++ri)
        po[oc][ri] = __builtin_amdgcn_mfma_f32_16x16x32_bf16(w, af[ri], po[oc][ri], 0, 0, 0);
    }
  }
  float* ob = out + (size_t)b * 8192;
#pragma unroll
  for (int oc = 0; oc < 2; ++oc) {
    float4v pb4 = *(const float4v*)&proj_b[h * 32 + oc * 16 + 4 * g];
#pragma unroll
    for (int ri = 0; ri < 4; ++ri) {
      int row = 16 * ri + l15;
      float4 o = make_float4(po[oc][ri][0] + pb4[0], po[oc][ri][1] + pb4[1],
                             po[oc][ri][2] + pb4[2], po[oc][ri][3] + pb4[3]);
      *(float4*)&ob[row * 128 + h * 32 + oc * 16 + 4 * g] = o;
    }
  }
#undef LDA
}

extern "C" void kernel_launch(void* const* d_in, const int* in_sizes, int n_in,
                              void* d_out, int out_size, void* d_ws, size_t ws_size,
                              hipStream_t stream) {
  const float* x      = (const float*)d_in[0];
  const float* mask   = (const float*)d_in[1];
  const float* qkv_w  = (const float*)d_in[2];
  const float* qkv_b  = (const float*)d_in[3];
  const float* proj_w = (const float*)d_in[4];
  const float* proj_b = (const float*)d_in[5];
  const float* btab   = (const float*)d_in[6];
  const int*   ridx   = (const int*)d_in[7];
  unsigned short* ws  = (unsigned short*)d_ws;
  float* out = (float*)d_out;

  hipLaunchKernelGGL(prep_kernel, dim3(64), dim3(256), 0, stream, qkv_w, proj_w, btab, ridx, ws);
  hipLaunchKernelGGL(win_attn_kernel, dim3(8192), dim3(256), 0, stream,
                     x, mask, qkv_b, proj_b, ws, out);
}